// Round 12
// baseline (79.663 us; speedup 1.0000x reference)
//
#include <hip/hip_runtime.h>

#define NN 100000
#define NE 1600000
#define TT 12
#define HH 32
#define NB 391          // coarse buckets of 256 nodes (node bucket = d >> 8)
#define NCH 391         // scatter chunks = ceil(NE/CHUNK) (== NB by coincidence)
#define BSH 8
#define CHUNK 4096      // edges per scatter block
#define SORTCAP 4800    // per-bucket capacity (mean 4096, sigma 64 -> +11 sigma)
#define LOG2E 1.4426950408889634f

typedef unsigned int u32;

// ---------------- workspace layout (4-byte units), ~32.4 MB ----------------
// [0, 153280)          : offT (int[NCH][392]): per-chunk bucket-run offsets,
//                        entry 391 = chunk size sentinel
// [153280, 253296)     : nodebase[100001] (pad to 253312)
// [253312, 253712)     : bend[391]  (bucket end in rec2)
// [253712, 353712)     : dinv (float[NN])
// [353712, 1153712)    : xpb (u32[NN][8]) bf16x2-packed dinv[n]*x[n], 32B rows
// [1153712, 4353712)   : rec (int2[NE])   — chunk-ordered (bucket-runs in chunk)
// [4353712, 8107312)   : rec2 (int2[NB*4800]) — node-sorted, fixed bucket slots
// [8107312, 8107456)   : P params: Az[32],Bz[32],Ah2[32],Bh2[32],probs[12]
// No global counters -> NOTHING needs zeroing, no global atomics anywhere.
// Session lessons: R2 global float atomics forbidden (uncached 32B writes);
// R8 >2 LDS atomics/edge forbidden; R9 heavy work on 391-block grids loses
// ~40% of the chip to block imbalance; R10 scan-free fixed-slot layout -19us;
// R1/R11 edge-parallelism (lanes/node) is the binding resource in the gather.
// The ~41us __amd_rocclr_fillBufferAligned dispatches in rocprof are the
// harness's 256MiB workspace re-poison (reset phase) — NOT in the timed window.

// Pass 1 (no prerequisites): chunk-local counting sort by bucket; chunk is
// written back COALESCED at its own base; per-chunk run offsets go to offT.
// Grid NCH+1: the extra block (blockIdx == NCH) folds the gate params.
__global__ __launch_bounds__(512) void k_scatter(const int* __restrict__ ei,
                                                 const float* __restrict__ ew,
                                                 int2* __restrict__ rec,
                                                 int* __restrict__ offT,
                                                 const float* __restrict__ czw, const float* __restrict__ czb,
                                                 const float* __restrict__ lzw, const float* __restrict__ lzb,
                                                 const float* __restrict__ chw, const float* __restrict__ chb,
                                                 const float* __restrict__ lhw, const float* __restrict__ lhb,
                                                 const float* __restrict__ att, float* __restrict__ P) {
    int t = threadIdx.x;
    if (blockIdx.x == NCH) {   // ---- gate-param block ----
        if (t < HH) {
            int j = t;
            float az = 0.f, bz = 0.f, ah = 0.f, bh = 0.f;
            for (int k = 0; k < HH; ++k) {
                float lz = lzw[k * HH + j];
                float lh = lhw[k * HH + j];
                az = fmaf(czw[k], lz, az);
                bz = fmaf(czb[k], lz, bz);
                ah = fmaf(chw[k], lh, ah);
                bh = fmaf(chb[k], lh, bh);
            }
            // pre-scale by log2e so the hot loop uses raw v_exp_f32 (2^x)
            P[j]        = az * LOG2E;
            P[HH + j]   = (bz + lzb[j]) * LOG2E;
            P[2*HH + j] = 2.0f * LOG2E * ah;          // tanh(x) = f(2^(2x*log2e))
            P[3*HH + j] = 2.0f * LOG2E * (bh + lhb[j]);
        }
        if (t == 0) {
            float m = -1e30f;
            for (int q = 0; q < TT; ++q) m = fmaxf(m, att[q]);
            float ex[TT]; float s = 0.f;
            for (int q = 0; q < TT; ++q) { ex[q] = expf(att[q] - m); s += ex[q]; }
            for (int q = 0; q < TT; ++q) P[4*HH + q] = ex[q] / s;
        }
        return;
    }
    __shared__ int2 cbuf[CHUNK];                 // 32 KB
    __shared__ int sc[512];
    __shared__ int cnt[NB], off[NB], cur[NB];
    int base = blockIdx.x * CHUNK;
    int m = min(CHUNK, NE - base);
    for (int j = t; j < NB; j += 512) { cnt[j] = 0; cur[j] = 0; }
    __syncthreads();
    int dsts[8], srcs[8]; float ews[8];
#pragma unroll
    for (int i = 0; i < 8; ++i) {
        int k = t + i * 512;
        if (k < m) {
            int e = base + k;
            dsts[i] = ei[NE + e]; srcs[i] = ei[e]; ews[i] = ew[e];
            atomicAdd(&cnt[dsts[i] >> BSH], 1);
        }
    }
    __syncthreads();
    int v = (t < NB) ? cnt[t] : 0;
    sc[t] = v;
    __syncthreads();
    for (int o = 1; o < 512; o <<= 1) {
        int add = (t >= o) ? sc[t - o] : 0;
        __syncthreads();
        sc[t] += add;
        __syncthreads();
    }
    if (t < NB) {
        int e = sc[t] - v;
        off[t] = e;
        offT[blockIdx.x * 392 + t] = e;
    }
    if (t == 0) offT[blockIdx.x * 392 + NB] = m;   // sentinel = chunk size
    __syncthreads();
#pragma unroll
    for (int i = 0; i < 8; ++i) {
        int k = t + i * 512;
        if (k < m) {
            int b = dsts[i] >> BSH;
            int p = off[b] + atomicAdd(&cur[b], 1);
            // src in bits 0..16 (100000 < 2^17), node-local dst (d&255) in 17..24
            cbuf[p] = make_int2(srcs[i] | ((dsts[i] & 255) << 17), __float_as_int(ews[i]));
        }
    }
    __syncthreads();
    for (int k = t; k < m; k += 512) rec[base + k] = cbuf[k];   // coalesced
}

__device__ __forceinline__ u32 bfpack(float a, float b) {  // RNE bf16 pair
    u32 ua = __float_as_uint(a), ub = __float_as_uint(b);
    ua = (ua + 0x7FFFu + ((ua >> 16) & 1u)) >> 16;
    ub = (ub + 0x7FFFu + ((ub >> 16) & 1u)) >> 16;
    return ua | (ub << 16);
}

// Pass 2: one block per bucket. Gathers the bucket's ~4096 records from 391
// short chunk-runs via offT (thread c copies run c: ~10.5 contiguous int2),
// then histogram+wsum (2 LDS atomics/record), scan, dinv + bf16 xpb row
// build, sorted rewrite into the bucket's fixed rec2 slot [b*4800, b*4800+m).
__global__ __launch_bounds__(512) void k_sort(const int2* __restrict__ rec,
                                              const int* __restrict__ offT,
                                              int2* __restrict__ rec2,
                                              int* __restrict__ nodebase,
                                              int* __restrict__ bend,
                                              float* __restrict__ dinv,
                                              const float* __restrict__ x,
                                              u32* __restrict__ xpb) {
    __shared__ int2 buf[SORTCAP];                // 37.5 KB
    __shared__ int sc[512];
    __shared__ int cnt[256], cur[256];
    __shared__ float wsum[256], dvs[256];
    int b = blockIdx.x, t = threadIdx.x;
    // ---- run lengths + scan -> destination offsets in buf ----
    int o0 = 0, len = 0;
    if (t < NCH) {
        o0 = offT[t * 392 + b];
        len = offT[t * 392 + b + 1] - o0;
    }
    sc[t] = len;
    __syncthreads();
    for (int o = 1; o < 512; o <<= 1) {
        int add = (t >= o) ? sc[t - o] : 0;
        __syncthreads();
        sc[t] += add;
        __syncthreads();
    }
    int rdst = sc[t] - len;
    int m = min(sc[511], SORTCAP);
    if (t < 256) { cnt[t] = 0; wsum[t] = 0.f; }
    __syncthreads();
    // ---- ragged gather + histogram + wsum ----
    for (int j = 0; j < len; ++j) {
        int d = rdst + j;
        if (d >= SORTCAP) break;
        int2 r = rec[t * CHUNK + o0 + j];
        buf[d] = r;
        int loc = (r.x >> 17) & 255;
        atomicAdd(&cnt[loc], 1);
        atomicAdd(&wsum[loc], __int_as_float(r.y));
    }
    __syncthreads();
    // ---- per-node scan, dinv, nodebase, xpb row ----
    int v = (t < 256) ? cnt[t] : 0;
    sc[t] = v;
    __syncthreads();
    for (int o = 1; o < 256; o <<= 1) {
        int add = (t >= o) ? sc[t - o] : 0;
        __syncthreads();
        sc[t] += add;
        __syncthreads();
    }
    if (t < 256) {
        int e = sc[t] - v;  // exclusive prefix
        cur[t] = e;
        float dv = rsqrtf(1.0f + wsum[t]);  // +1 = self loop
        dvs[t] = dv;
        int n = (b << BSH) + t;
        if (n < NN) {
            dinv[n] = dv;
            nodebase[n] = b * SORTCAP + e;
            const float4* xr = (const float4*)(x + (long)n * TT);
            float4 v0 = xr[0], v1 = xr[1], v2 = xr[2];
            uint4* xo = (uint4*)(xpb + ((long)n << 3));
            uint4 w0, w1;
            w0.x = bfpack(v0.x * dv, v0.y * dv);
            w0.y = bfpack(v0.z * dv, v0.w * dv);
            w0.z = bfpack(v1.x * dv, v1.y * dv);
            w0.w = bfpack(v1.z * dv, v1.w * dv);
            w1.x = bfpack(v2.x * dv, v2.y * dv);
            w1.y = bfpack(v2.z * dv, v2.w * dv);
            w1.z = 0u; w1.w = 0u;
            xo[0] = w0; xo[1] = w1;
        }
    }
    if (t == 0) {
        bend[b] = b * SORTCAP + m;
        if (b == NB - 1) nodebase[NN] = b * SORTCAP + m;
    }
    __syncthreads();
    // ---- sorted rewrite ----
    for (int k = t; k < m; k += 512) {
        int2 r = buf[k];
        int loc = (r.x >> 17) & 255;
        int p = atomicAdd(&cur[loc], 1);
        float w2 = __int_as_float(r.y) * dvs[loc];  // fold dinv[dst] into weight
        rec2[b * SORTCAP + p] = make_int2(r.x & 0x1FFFF, __float_as_int(w2));
    }
}

#define BLO(w) __uint_as_float((w) << 16)
#define BHI(w) __uint_as_float((w) & 0xFFFF0000u)

// 32 lanes per node (R1: 1->8 lanes +27us, R11: 8->16 +6.4us; mean degree 16,
// P(deg>32) ~ 1e-4 -> the gather loop is now effectively loop-free: each lane
// issues at most one rec2 load + one xpb row load, all parallel — the
// dependent chain is at its floor of 2 loads). Each half-wave reads 32
// consecutive int2 = 256B contiguous rec2. Epilogue: 1 channel/lane,
// 5-level shfl reduce. 3.2M threads = 6250x512 exactly.
__global__ __launch_bounds__(512) void k_fused(const int* __restrict__ nodebase,
                                               const int* __restrict__ bend,
                                               const int2* __restrict__ rec2,
                                               const float* __restrict__ dinv,
                                               const u32* __restrict__ xpb,
                                               const float* __restrict__ P,
                                               const float* __restrict__ hw,
                                               const float* __restrict__ hb,
                                               float* __restrict__ out) {
    int g = blockIdx.x * 512 + threadIdx.x;
    int n = g >> 5, sub = g & 31;
    float a[TT];
#pragma unroll
    for (int q = 0; q < TT; ++q) a[q] = 0.f;
    if (sub == 0) {
        float di = dinv[n];   // self term = dinv * (bf16 row)
        const uint4* xr = (const uint4*)(xpb + ((long)n << 3));
        uint4 h0 = xr[0];
        uint2 h1 = *(const uint2*)(xr + 1);
        a[0]  = di * BLO(h0.x); a[1]  = di * BHI(h0.x);
        a[2]  = di * BLO(h0.y); a[3]  = di * BHI(h0.y);
        a[4]  = di * BLO(h0.z); a[5]  = di * BHI(h0.z);
        a[6]  = di * BLO(h0.w); a[7]  = di * BHI(h0.w);
        a[8]  = di * BLO(h1.x); a[9]  = di * BHI(h1.x);
        a[10] = di * BLO(h1.y); a[11] = di * BHI(h1.y);
    }
    int k0 = nodebase[n];
    int k1 = ((n & 255) == 255) ? bend[n >> 8] : nodebase[n + 1];
    for (int k = k0 + sub; k < k1; k += 32) {
        int2 r = rec2[k];
        float c = __int_as_float(r.y);  // = ew * dinv[dst]; dinv[src] in xpb
        const uint4* xs = (const uint4*)(xpb + ((long)r.x << 3));
        uint4 h0 = xs[0];                       // periods 0-7 (16B)
        uint2 h1 = *(const uint2*)(xs + 1);     // periods 8-11 (8B, same line)
        a[0]  = fmaf(c, BLO(h0.x), a[0]);  a[1]  = fmaf(c, BHI(h0.x), a[1]);
        a[2]  = fmaf(c, BLO(h0.y), a[2]);  a[3]  = fmaf(c, BHI(h0.y), a[3]);
        a[4]  = fmaf(c, BLO(h0.z), a[4]);  a[5]  = fmaf(c, BHI(h0.z), a[5]);
        a[6]  = fmaf(c, BLO(h0.w), a[6]);  a[7]  = fmaf(c, BHI(h0.w), a[7]);
        a[8]  = fmaf(c, BLO(h1.x), a[8]);  a[9]  = fmaf(c, BHI(h1.x), a[9]);
        a[10] = fmaf(c, BLO(h1.y), a[10]); a[11] = fmaf(c, BHI(h1.y), a[11]);
    }
    // tree-reduce the 12 accumulators across the 32 lanes of this node
#pragma unroll
    for (int q = 0; q < TT; ++q) {
        float v = a[q];
        v += __shfl_xor(v, 1);
        v += __shfl_xor(v, 2);
        v += __shfl_xor(v, 4);
        v += __shfl_xor(v, 8);
        v += __shfl_xor(v, 16);
        a[q] = v;
    }
    // --- epilogue: gates + attention + head, 1 hidden channel per lane ---
    float p[TT];
#pragma unroll
    for (int q = 0; q < TT; ++q) p[q] = P[4*HH + q];
    int j = sub;
    float Az = P[j], Bz = P[HH + j], Ah2 = P[2*HH + j], Bh2 = P[3*HH + j];
    float w = hw[j];
    float acc = 0.f;
#pragma unroll
    for (int q = 0; q < TT; ++q) {
        float xz = fmaf(a[q], Az, Bz);                   // log2-domain
        float xh = fminf(fmaf(a[q], Ah2, Bh2), 115.f);   // keep eh finite
        float ez = __builtin_amdgcn_exp2f(xz);  // e^orig_xz
        float eh = __builtin_amdgcn_exp2f(xh);  // e^(2*orig_xh)
        float den = (1.f + ez) * (eh + 1.f);
        float num = eh - 1.f;
        acc = fmaf(p[q] * num, __builtin_amdgcn_rcpf(den), acc);
    }
    float o = fmaxf(acc, 0.f) * w;
    o += __shfl_xor(o, 1);
    o += __shfl_xor(o, 2);
    o += __shfl_xor(o, 4);
    o += __shfl_xor(o, 8);
    o += __shfl_xor(o, 16);
    if (sub == 0) out[n] = o + hb[0];
}

extern "C" void kernel_launch(void* const* d_in, const int* in_sizes, int n_in,
                              void* d_out, int out_size, void* d_ws, size_t ws_size,
                              hipStream_t stream) {
    const float* x    = (const float*)d_in[0];
    const int*   ei   = (const int*)d_in[1];
    const float* ew   = (const float*)d_in[2];
    const float* att  = (const float*)d_in[3];
    const float* czw  = (const float*)d_in[4];
    const float* czb  = (const float*)d_in[5];
    const float* lzw  = (const float*)d_in[6];
    const float* lzb  = (const float*)d_in[7];
    // conv_r / lin_r (d_in[8..11]) are mathematically dead: H=0 -> H*R=0, Z*H=0.
    const float* chw  = (const float*)d_in[12];
    const float* chb  = (const float*)d_in[13];
    const float* lhw  = (const float*)d_in[14];
    const float* lhb  = (const float*)d_in[15];
    const float* hw   = (const float*)d_in[16];
    const float* hb   = (const float*)d_in[17];
    float* out = (float*)d_out;

    int*  ws32     = (int*)d_ws;
    int*  offT     = ws32;                     // NCH*392 = 153272 (pad 153280)
    int*  nodebase = ws32 + 153280;            // 100001 (pad to 253312)
    int*  bend     = ws32 + 253312;            // 391 (pad to 253712)
    float* dinv    = (float*)(ws32 + 253712);  // NN
    u32*  xpb      = (u32*)(ws32 + 353712);    // NN*8 u32, 32B rows (3.2MB)
    int2* rec      = (int2*)(ws32 + 1153712);  // NE int2 (chunk-ordered)
    int2* rec2     = (int2*)(ws32 + 4353712);  // NB*4800 int2 (node-sorted)
    float* P       = (float*)(ws32 + 8107312); // 144

    k_scatter<<<NCH + 1, 512, 0, stream>>>(ei, ew, rec, offT,
                                           czw, czb, lzw, lzb, chw, chb, lhw, lhb, att, P);
    k_sort<<<NB, 512, 0, stream>>>(rec, offT, rec2, nodebase, bend, dinv, x, xpb);
    k_fused<<<(NN * 32) / 512, 512, 0, stream>>>(nodebase, bend, rec2, dinv, xpb,
                                                 P, hw, hb, out);
}

// Round 13
// 76.165 us; speedup vs baseline: 1.0459x; 1.0459x over previous
//
#include <hip/hip_runtime.h>

#define NN 100000
#define NE 1600000
#define TT 12
#define HH 32
#define NB 1563         // buckets of 64 nodes (bucket = dst >> 6)
#define NBP 1564        // padded bucket count (+1 sentinel slot in offT rows)
#define NCH 512         // scatter chunks: 512 = exactly 2 blocks/CU, NE = 512*3125
#define BSH 6
#define CHUNK 3125      // edges per scatter chunk
#define SORTCAP 1376    // per-bucket capacity (mean 1024, sigma 32 -> +11 sigma)
#define LOG2E 1.4426950408889634f

typedef unsigned int u32;

// ---------------- workspace layout (4-byte units), ~37.2 MB ----------------
// [0, 800768)          : offT (int[NCH][NBP]): per-chunk bucket-run offsets;
//                        entry 1563 = sentinel (exclusive prefix of padded
//                        empty bucket == chunk size) — falls out of the scan
// [800800, 900801)     : nodebase[100001] (pad to 900816)
// [900816, 902379)     : bend[1563] (pad to 902400)
// [902400, 1002400)    : dinv (float[NN])
// [1002400, 1802400)   : xpb (u32[NN][8]) bf16x2-packed dinv[n]*x[n], 32B rows
// [1802400, 5002400)   : rec (int2[NE]) — chunk-ordered (bucket-runs in chunk)
// [5002400, 9303776)   : rec2 (int2[NB*1376]) — node-sorted, fixed bucket slots
// [9303776, 9303920)   : P params: Az[32],Bz[32],Ah2[32],Bh2[32],probs[12]
// No global counters -> nothing to zero, no global atomics anywhere.
// Session lessons: R2 global float atomics forbidden; R8 >2 LDS atomics/edge
// forbidden; R9/R12 grid-quantization: heavy 391-block grids run 2 rounds on
// 256 CUs (1.53 rounds of work) — use block counts that pack (512 = 2/CU
// exact) or many small blocks (1563 @ 14KB LDS -> deep backfill); R10
// scan-free fixed-slot layout; R11/R12 lanes/node optimum is 16 (8->16 +6.4us,
// 16->32 -8.4us: reduce+epilogue per-thread overhead doubles, total fixed).
// The ~41us fillBufferAligned dispatches = harness 256MiB re-poison, untimed.

// Pass 1 (no prerequisites): chunk-local counting sort by bucket; chunk
// written back COALESCED at its own base; run offsets -> offT. Grid NCH+1:
// the extra block folds the gate params.
__global__ __launch_bounds__(512) void k_scatter(const int* __restrict__ ei,
                                                 const float* __restrict__ ew,
                                                 int2* __restrict__ rec,
                                                 int* __restrict__ offT,
                                                 const float* __restrict__ czw, const float* __restrict__ czb,
                                                 const float* __restrict__ lzw, const float* __restrict__ lzb,
                                                 const float* __restrict__ chw, const float* __restrict__ chb,
                                                 const float* __restrict__ lhw, const float* __restrict__ lhb,
                                                 const float* __restrict__ att, float* __restrict__ P) {
    int t = threadIdx.x;
    if (blockIdx.x == NCH) {   // ---- gate-param block ----
        if (t < HH) {
            int j = t;
            float az = 0.f, bz = 0.f, ah = 0.f, bh = 0.f;
            for (int k = 0; k < HH; ++k) {
                float lz = lzw[k * HH + j];
                float lh = lhw[k * HH + j];
                az = fmaf(czw[k], lz, az);
                bz = fmaf(czb[k], lz, bz);
                ah = fmaf(chw[k], lh, ah);
                bh = fmaf(chb[k], lh, bh);
            }
            // pre-scale by log2e so the hot loop uses raw v_exp_f32 (2^x)
            P[j]        = az * LOG2E;
            P[HH + j]   = (bz + lzb[j]) * LOG2E;
            P[2*HH + j] = 2.0f * LOG2E * ah;          // tanh(x) = f(2^(2x*log2e))
            P[3*HH + j] = 2.0f * LOG2E * (bh + lhb[j]);
        }
        if (t == 0) {
            float m = -1e30f;
            for (int q = 0; q < TT; ++q) m = fmaxf(m, att[q]);
            float ex[TT]; float s = 0.f;
            for (int q = 0; q < TT; ++q) { ex[q] = expf(att[q] - m); s += ex[q]; }
            for (int q = 0; q < TT; ++q) P[4*HH + q] = ex[q] / s;
        }
        return;
    }
    __shared__ int2 cbuf[CHUNK];                 // 25 KB
    __shared__ int sc[512];
    __shared__ int cnt[NBP], off[NBP], cur[NB];  // ~18.7 KB (cnt[1563] stays 0)
    int base = blockIdx.x * CHUNK;
    int m = min(CHUNK, NE - base);               // == CHUNK (NE = NCH*CHUNK)
    for (int j = t; j < NBP; j += 512) { cnt[j] = 0; if (j < NB) cur[j] = 0; }
    __syncthreads();
    int dsts[7], srcs[7]; float ews[7];
#pragma unroll
    for (int i = 0; i < 7; ++i) {
        int k = t + i * 512;
        if (k < m) {
            int e = base + k;
            dsts[i] = ei[NE + e]; srcs[i] = ei[e]; ews[i] = ew[e];
            atomicAdd(&cnt[dsts[i] >> BSH], 1);
        }
    }
    __syncthreads();
    // scan 1564 bucket counts: thread t<391 owns 4 consecutive buckets
    int j0 = 4 * t;
    int c4[4]; int s = 0;
    if (t < 391) {
#pragma unroll
        for (int i = 0; i < 4; ++i) { c4[i] = cnt[j0 + i]; s += c4[i]; }
    }
    sc[t] = (t < 391) ? s : 0;
    __syncthreads();
    for (int o = 1; o < 512; o <<= 1) {
        int add = (t >= o) ? sc[t - o] : 0;
        __syncthreads();
        sc[t] += add;
        __syncthreads();
    }
    if (t < 391) {
        int e = sc[t] - s;  // exclusive prefix of this 4-bucket group
        int rowbase = blockIdx.x * NBP;
#pragma unroll
        for (int i = 0; i < 4; ++i) {
            off[j0 + i] = e;
            offT[rowbase + j0 + i] = e;   // bucket 1563's entry == m (sentinel)
            e += c4[i];
        }
    }
    __syncthreads();
#pragma unroll
    for (int i = 0; i < 7; ++i) {
        int k = t + i * 512;
        if (k < m) {
            int b = dsts[i] >> BSH;
            int p = off[b] + atomicAdd(&cur[b], 1);
            // src in bits 0..16 (100000 < 2^17), node-local dst (d&63) in 17..22
            cbuf[p] = make_int2(srcs[i] | ((dsts[i] & 63) << 17), __float_as_int(ews[i]));
        }
    }
    __syncthreads();
    for (int k = t; k < m; k += 512) rec[base + k] = cbuf[k];   // coalesced
}

__device__ __forceinline__ u32 bfpack(float a, float b) {  // RNE bf16 pair
    u32 ua = __float_as_uint(a), ub = __float_as_uint(b);
    ua = (ua + 0x7FFFu + ((ua >> 16) & 1u)) >> 16;
    ub = (ub + 0x7FFFu + ((ub >> 16) & 1u)) >> 16;
    return ua | (ub << 16);
}

// Pass 2: one block per bucket (1563 small blocks, ~14KB LDS -> deep backfill,
// ~1.2x ideal makespan vs 2.0x at 391 heavy blocks). Gathers the bucket's
// ~1024 records from 512 chunk-runs (1 run/thread, mean 2 each), then
// histogram+wsum (2 LDS atomics/record), 64-node scan, dinv + bf16 xpb row
// build, sorted rewrite into the bucket's fixed rec2 slot [b*1376, b*1376+m).
__global__ __launch_bounds__(512) void k_sort(const int2* __restrict__ rec,
                                              const int* __restrict__ offT,
                                              int2* __restrict__ rec2,
                                              int* __restrict__ nodebase,
                                              int* __restrict__ bend,
                                              float* __restrict__ dinv,
                                              const float* __restrict__ x,
                                              u32* __restrict__ xpb) {
    __shared__ int2 buf[SORTCAP];                // 11 KB
    __shared__ int sc[512];
    __shared__ int cnt[64], cur[64];
    __shared__ float wsum[64], dvs[64];
    int b = blockIdx.x, t = threadIdx.x;
    // ---- run lengths + scan -> destination offsets in buf ----
    int o0 = offT[t * NBP + b];
    int len = offT[t * NBP + b + 1] - o0;        // b+1 <= 1563 (sentinel) OK
    sc[t] = len;
    if (t < 64) { cnt[t] = 0; wsum[t] = 0.f; }
    __syncthreads();
    for (int o = 1; o < 512; o <<= 1) {
        int add = (t >= o) ? sc[t - o] : 0;
        __syncthreads();
        sc[t] += add;
        __syncthreads();
    }
    int rdst = sc[t] - len;
    int m = min(sc[511], SORTCAP);
    // ---- ragged gather + histogram + wsum ----
    for (int j = 0; j < len; ++j) {
        int d = rdst + j;
        if (d >= SORTCAP) break;
        int2 r = rec[t * CHUNK + o0 + j];
        buf[d] = r;
        int loc = (r.x >> 17) & 63;
        atomicAdd(&cnt[loc], 1);
        atomicAdd(&wsum[loc], __int_as_float(r.y));
    }
    __syncthreads();
    // ---- per-node scan (64), dinv, nodebase, xpb row ----
    int v = (t < 64) ? cnt[t] : 0;
    if (t < 64) sc[t] = v;
    __syncthreads();
    for (int o = 1; o < 64; o <<= 1) {
        int add = (t < 64 && t >= o) ? sc[t - o] : 0;
        __syncthreads();
        if (t < 64) sc[t] += add;
        __syncthreads();
    }
    if (t < 64) {
        int e = sc[t] - v;  // exclusive prefix
        cur[t] = e;
        float dv = rsqrtf(1.0f + wsum[t]);  // +1 = self loop
        dvs[t] = dv;
        int n = (b << BSH) + t;
        if (n < NN) {
            dinv[n] = dv;
            nodebase[n] = b * SORTCAP + e;
            const float4* xr = (const float4*)(x + (long)n * TT);
            float4 v0 = xr[0], v1 = xr[1], v2 = xr[2];
            uint4* xo = (uint4*)(xpb + ((long)n << 3));
            uint4 w0, w1;
            w0.x = bfpack(v0.x * dv, v0.y * dv);
            w0.y = bfpack(v0.z * dv, v0.w * dv);
            w0.z = bfpack(v1.x * dv, v1.y * dv);
            w0.w = bfpack(v1.z * dv, v1.w * dv);
            w1.x = bfpack(v2.x * dv, v2.y * dv);
            w1.y = bfpack(v2.z * dv, v2.w * dv);
            w1.z = 0u; w1.w = 0u;
            xo[0] = w0; xo[1] = w1;
        }
    }
    if (t == 0) {
        bend[b] = b * SORTCAP + m;
        if (b == NB - 1) nodebase[NN] = b * SORTCAP + m;
    }
    __syncthreads();
    // ---- sorted rewrite ----
    for (int k = t; k < m; k += 512) {
        int2 r = buf[k];
        int loc = (r.x >> 17) & 63;
        int p = atomicAdd(&cur[loc], 1);
        float w2 = __int_as_float(r.y) * dvs[loc];  // fold dinv[dst] into weight
        rec2[b * SORTCAP + p] = make_int2(r.x & 0x1FFFF, __float_as_int(w2));
    }
}

#define BLO(w) __uint_as_float((w) << 16)
#define BHI(w) __uint_as_float((w) & 0xFFFF0000u)

// 16 lanes per node — the measured optimum (R11; 32 lanes regressed in R12:
// reduce+epilogue per-thread overhead doubles while total work is fixed).
// Each lane walks every-16th record (coalesced rec2), one 32B bf16 row per
// edge, 4-level shfl reduce, 2 channels/lane exp2-domain epilogue.
__global__ __launch_bounds__(512) void k_fused(const int* __restrict__ nodebase,
                                               const int* __restrict__ bend,
                                               const int2* __restrict__ rec2,
                                               const float* __restrict__ dinv,
                                               const u32* __restrict__ xpb,
                                               const float* __restrict__ P,
                                               const float* __restrict__ hw,
                                               const float* __restrict__ hb,
                                               float* __restrict__ out) {
    int g = blockIdx.x * 512 + threadIdx.x;
    int n = g >> 4, sub = g & 15;   // NN*16 = 1.6M = 3125*512 exactly
    float a[TT];
#pragma unroll
    for (int q = 0; q < TT; ++q) a[q] = 0.f;
    if (sub == 0) {
        float di = dinv[n];   // self term = dinv * (bf16 row)
        const uint4* xr = (const uint4*)(xpb + ((long)n << 3));
        uint4 h0 = xr[0];
        uint2 h1 = *(const uint2*)(xr + 1);
        a[0]  = di * BLO(h0.x); a[1]  = di * BHI(h0.x);
        a[2]  = di * BLO(h0.y); a[3]  = di * BHI(h0.y);
        a[4]  = di * BLO(h0.z); a[5]  = di * BHI(h0.z);
        a[6]  = di * BLO(h0.w); a[7]  = di * BHI(h0.w);
        a[8]  = di * BLO(h1.x); a[9]  = di * BHI(h1.x);
        a[10] = di * BLO(h1.y); a[11] = di * BHI(h1.y);
    }
    int k0 = nodebase[n];
    int k1 = ((n & 63) == 63) ? bend[n >> 6] : nodebase[n + 1];
    for (int k = k0 + sub; k < k1; k += 16) {
        int2 r = rec2[k];
        float c = __int_as_float(r.y);  // = ew * dinv[dst]; dinv[src] in xpb
        const uint4* xs = (const uint4*)(xpb + ((long)r.x << 3));
        uint4 h0 = xs[0];                       // periods 0-7 (16B)
        uint2 h1 = *(const uint2*)(xs + 1);     // periods 8-11 (8B, same line)
        a[0]  = fmaf(c, BLO(h0.x), a[0]);  a[1]  = fmaf(c, BHI(h0.x), a[1]);
        a[2]  = fmaf(c, BLO(h0.y), a[2]);  a[3]  = fmaf(c, BHI(h0.y), a[3]);
        a[4]  = fmaf(c, BLO(h0.z), a[4]);  a[5]  = fmaf(c, BHI(h0.z), a[5]);
        a[6]  = fmaf(c, BLO(h0.w), a[6]);  a[7]  = fmaf(c, BHI(h0.w), a[7]);
        a[8]  = fmaf(c, BLO(h1.x), a[8]);  a[9]  = fmaf(c, BHI(h1.x), a[9]);
        a[10] = fmaf(c, BLO(h1.y), a[10]); a[11] = fmaf(c, BHI(h1.y), a[11]);
    }
    // tree-reduce the 12 accumulators across the 16 lanes of this node
#pragma unroll
    for (int q = 0; q < TT; ++q) {
        float v = a[q];
        v += __shfl_xor(v, 1);
        v += __shfl_xor(v, 2);
        v += __shfl_xor(v, 4);
        v += __shfl_xor(v, 8);
        a[q] = v;
    }
    // --- epilogue: gates + attention + head, 2 hidden channels per lane ---
    float p[TT];
#pragma unroll
    for (int q = 0; q < TT; ++q) p[q] = P[4*HH + q];
    float o = 0.f;
#pragma unroll
    for (int jj = 0; jj < 2; ++jj) {
        int j = (jj << 4) | sub;
        float Az = P[j], Bz = P[HH + j], Ah2 = P[2*HH + j], Bh2 = P[3*HH + j];
        float w = hw[j];
        float acc = 0.f;
#pragma unroll
        for (int q = 0; q < TT; ++q) {
            float xz = fmaf(a[q], Az, Bz);                   // log2-domain
            float xh = fminf(fmaf(a[q], Ah2, Bh2), 115.f);   // keep eh finite
            float ez = __builtin_amdgcn_exp2f(xz);  // e^orig_xz
            float eh = __builtin_amdgcn_exp2f(xh);  // e^(2*orig_xh)
            float den = (1.f + ez) * (eh + 1.f);
            float num = eh - 1.f;
            acc = fmaf(p[q] * num, __builtin_amdgcn_rcpf(den), acc);
        }
        o = fmaf(fmaxf(acc, 0.f), w, o);
    }
    o += __shfl_xor(o, 1);
    o += __shfl_xor(o, 2);
    o += __shfl_xor(o, 4);
    o += __shfl_xor(o, 8);
    if (sub == 0) out[n] = o + hb[0];
}

extern "C" void kernel_launch(void* const* d_in, const int* in_sizes, int n_in,
                              void* d_out, int out_size, void* d_ws, size_t ws_size,
                              hipStream_t stream) {
    const float* x    = (const float*)d_in[0];
    const int*   ei   = (const int*)d_in[1];
    const float* ew   = (const float*)d_in[2];
    const float* att  = (const float*)d_in[3];
    const float* czw  = (const float*)d_in[4];
    const float* czb  = (const float*)d_in[5];
    const float* lzw  = (const float*)d_in[6];
    const float* lzb  = (const float*)d_in[7];
    // conv_r / lin_r (d_in[8..11]) are mathematically dead: H=0 -> H*R=0, Z*H=0.
    const float* chw  = (const float*)d_in[12];
    const float* chb  = (const float*)d_in[13];
    const float* lhw  = (const float*)d_in[14];
    const float* lhb  = (const float*)d_in[15];
    const float* hw   = (const float*)d_in[16];
    const float* hb   = (const float*)d_in[17];
    float* out = (float*)d_out;

    int*  ws32     = (int*)d_ws;
    int*  offT     = ws32;                     // NCH*NBP = 800768 (pad 800800)
    int*  nodebase = ws32 + 800800;            // 100001 (pad to 900816)
    int*  bend     = ws32 + 900816;            // 1563 (pad to 902400)
    float* dinv    = (float*)(ws32 + 902400);  // NN
    u32*  xpb      = (u32*)(ws32 + 1002400);   // NN*8 u32, 32B rows (3.2MB)
    int2* rec      = (int2*)(ws32 + 1802400);  // NE int2 (chunk-ordered)
    int2* rec2     = (int2*)(ws32 + 5002400);  // NB*1376 int2 (node-sorted)
    float* P       = (float*)(ws32 + 9303776); // 144

    k_scatter<<<NCH + 1, 512, 0, stream>>>(ei, ew, rec, offT,
                                           czw, czb, lzw, lzb, chw, chb, lhw, lhb, att, P);
    k_sort<<<NB, 512, 0, stream>>>(rec, offT, rec2, nodebase, bend, dinv, x, xpb);
    k_fused<<<(NN * 16) / 512, 512, 0, stream>>>(nodebase, bend, rec2, dinv, xpb,
                                                 P, hw, hb, out);
}

// Round 14
// 70.209 us; speedup vs baseline: 1.1347x; 1.0848x over previous
//
#include <hip/hip_runtime.h>

#define NN 100000
#define NE 1600000
#define TT 12
#define HH 32
#define NBUK 512        // sort buckets of BDIV nodes; 512 = fully resident at 4/CU
#define BDIV 196        // nodes per bucket (dst/196; max bucket index 510)
#define NCH 512         // scatter chunks; NE = 512*3125 exactly
#define CHUNK 3125      // edges per scatter chunk
#define SORTCAP 3776    // per-bucket capacity (mean 3125, sigma 56 -> +11 sigma)
#define LOG2E 1.4426950408889634f

typedef unsigned int u32;

// ---------------- workspace layout (4-byte units), ~33.3 MB ----------------
// [0, 262656)          : offT (int[NCH][513]): per-chunk bucket-run offsets;
//                        entry 512 = chunk-size sentinel
// [262656, 362656)     : nodebase[100000]
// [362656, 363168)     : bend[512]  (bucket end in rec2)
// [363168, 463168)     : dinv (float[NN])
// [463168, 1263168)    : xpb (u32[NN][8]) bf16x2-packed dinv[n]*x[n], 32B rows
// [1263168, 4463168)   : rec (int2[NE]) — chunk-ordered (bucket-runs in chunk)
// [4463168, 8329792)   : rec2 (int2[NBUK*3776]) — node-sorted, fixed bucket slots
// [8329792, 8329936)   : P params: Az[32],Bz[32],Ah2[32],Bh2[32],probs[12]
// No global counters -> nothing to zero, no global atomics anywhere.
// Session lessons: R2 global float atomics forbidden; R8 >2 LDS atomics/edge
// forbidden; R9/R12 grid quantization: 391 heavy blocks = 2-round makespan on
// 256 CUs; R13 DON'T fix it by shrinking blocks (fixed scan cost per record
// 4x'd) — fix it by matching block count to resident slots (512 @ ~35KB LDS =
// 4/CU = all resident) while keeping ~3K records/block; R10 scan-free
// fixed-slot layout; R11/R12 lanes/node optimum is 16 (32 doubled
// reduce+epilogue overhead, -8.4us). The ~41us fillBufferAligned dispatches =
// harness 256MiB re-poison, outside the timed window.

// Pass 1 (no prerequisites): chunk-local counting sort by bucket; chunk
// written back COALESCED at its own base; run offsets -> offT. Grid NCH+1:
// the extra block folds the gate params.
__global__ __launch_bounds__(512) void k_scatter(const int* __restrict__ ei,
                                                 const float* __restrict__ ew,
                                                 int2* __restrict__ rec,
                                                 int* __restrict__ offT,
                                                 const float* __restrict__ czw, const float* __restrict__ czb,
                                                 const float* __restrict__ lzw, const float* __restrict__ lzb,
                                                 const float* __restrict__ chw, const float* __restrict__ chb,
                                                 const float* __restrict__ lhw, const float* __restrict__ lhb,
                                                 const float* __restrict__ att, float* __restrict__ P) {
    int t = threadIdx.x;
    if (blockIdx.x == NCH) {   // ---- gate-param block ----
        if (t < HH) {
            int j = t;
            float az = 0.f, bz = 0.f, ah = 0.f, bh = 0.f;
            for (int k = 0; k < HH; ++k) {
                float lz = lzw[k * HH + j];
                float lh = lhw[k * HH + j];
                az = fmaf(czw[k], lz, az);
                bz = fmaf(czb[k], lz, bz);
                ah = fmaf(chw[k], lh, ah);
                bh = fmaf(chb[k], lh, bh);
            }
            // pre-scale by log2e so the hot loop uses raw v_exp_f32 (2^x)
            P[j]        = az * LOG2E;
            P[HH + j]   = (bz + lzb[j]) * LOG2E;
            P[2*HH + j] = 2.0f * LOG2E * ah;          // tanh(x) = f(2^(2x*log2e))
            P[3*HH + j] = 2.0f * LOG2E * (bh + lhb[j]);
        }
        if (t == 0) {
            float m = -1e30f;
            for (int q = 0; q < TT; ++q) m = fmaxf(m, att[q]);
            float ex[TT]; float s = 0.f;
            for (int q = 0; q < TT; ++q) { ex[q] = expf(att[q] - m); s += ex[q]; }
            for (int q = 0; q < TT; ++q) P[4*HH + q] = ex[q] / s;
        }
        return;
    }
    __shared__ int2 cbuf[CHUNK];                 // 25 KB
    __shared__ int sc[512];
    __shared__ int cnt[NBUK], off[NBUK], cur[NBUK];  // 6 KB; ~33 KB total -> 4/CU
    int base = blockIdx.x * CHUNK;
    const int m = CHUNK;                         // NE = NCH*CHUNK exactly
    cnt[t] = 0; cur[t] = 0;
    __syncthreads();
    int dsts[7], srcs[7]; float ews[7];
#pragma unroll
    for (int i = 0; i < 7; ++i) {
        int k = t + i * 512;
        if (k < m) {
            int e = base + k;
            dsts[i] = ei[NE + e]; srcs[i] = ei[e]; ews[i] = ew[e];
            atomicAdd(&cnt[(u32)dsts[i] / BDIV], 1);
        }
    }
    __syncthreads();
    int v = cnt[t];
    sc[t] = v;
    __syncthreads();
    for (int o = 1; o < 512; o <<= 1) {
        int add = (t >= o) ? sc[t - o] : 0;
        __syncthreads();
        sc[t] += add;
        __syncthreads();
    }
    {
        int e = sc[t] - v;   // exclusive prefix; thread t owns bucket t
        off[t] = e;
        offT[blockIdx.x * 513 + t] = e;
    }
    if (t == 0) offT[blockIdx.x * 513 + NBUK] = m;   // sentinel = chunk size
    __syncthreads();
#pragma unroll
    for (int i = 0; i < 7; ++i) {
        int k = t + i * 512;
        if (k < m) {
            int b = (u32)dsts[i] / BDIV;
            int loc = dsts[i] - b * BDIV;        // 0..195, fits 8 bits
            int p = off[b] + atomicAdd(&cur[b], 1);
            // src in bits 0..16 (100000 < 2^17), node-local dst in bits 17..24
            cbuf[p] = make_int2(srcs[i] | (loc << 17), __float_as_int(ews[i]));
        }
    }
    __syncthreads();
    for (int k = t; k < m; k += 512) rec[base + k] = cbuf[k];   // coalesced
}

__device__ __forceinline__ u32 bfpack(float a, float b) {  // RNE bf16 pair
    u32 ua = __float_as_uint(a), ub = __float_as_uint(b);
    ua = (ua + 0x7FFFu + ((ua >> 16) & 1u)) >> 16;
    ub = (ub + 0x7FFFu + ((ub >> 16) & 1u)) >> 16;
    return ua | (ub << 16);
}

// Pass 2: one block per bucket (512 blocks, ~35KB LDS -> 4/CU -> ALL blocks
// co-resident; ~3125 records/block keeps scan fixed costs amortized — the
// R13 lesson). Gathers the bucket's records from 512 chunk-runs (1 run per
// thread, mean ~6), histogram+wsum (2 LDS atomics/record), 196-node scan,
// dinv + bf16 xpb row build, sorted rewrite into rec2 slot [b*3776, +m).
__global__ __launch_bounds__(512) void k_sort(const int2* __restrict__ rec,
                                              const int* __restrict__ offT,
                                              int2* __restrict__ rec2,
                                              int* __restrict__ nodebase,
                                              int* __restrict__ bend,
                                              float* __restrict__ dinv,
                                              const float* __restrict__ x,
                                              u32* __restrict__ xpb) {
    __shared__ int2 buf[SORTCAP];                // 29.5 KB
    __shared__ int sc[512];
    __shared__ int cnt[256], cur[256];
    __shared__ float wsum[256], dvs[256];
    int b = blockIdx.x, t = threadIdx.x;
    // ---- run lengths + scan -> destination offsets in buf ----
    int o0 = offT[t * 513 + b];
    int len = offT[t * 513 + b + 1] - o0;        // b+1 <= 512 (sentinel) OK
    sc[t] = len;
    if (t < 256) { cnt[t] = 0; wsum[t] = 0.f; }
    __syncthreads();
    for (int o = 1; o < 512; o <<= 1) {
        int add = (t >= o) ? sc[t - o] : 0;
        __syncthreads();
        sc[t] += add;
        __syncthreads();
    }
    int rdst = sc[t] - len;
    int m = min(sc[511], SORTCAP);
    // ---- ragged gather + histogram + wsum ----
    for (int j = 0; j < len; ++j) {
        int d = rdst + j;
        if (d >= SORTCAP) break;
        int2 r = rec[t * CHUNK + o0 + j];
        buf[d] = r;
        int loc = (r.x >> 17) & 255;
        atomicAdd(&cnt[loc], 1);
        atomicAdd(&wsum[loc], __int_as_float(r.y));
    }
    __syncthreads();
    // ---- per-node scan (196, padded to 256), dinv, nodebase, xpb row ----
    int v = (t < 256) ? cnt[t] : 0;
    if (t < 256) sc[t] = v;
    __syncthreads();
    for (int o = 1; o < 256; o <<= 1) {
        int add = (t < 256 && t >= o) ? sc[t - o] : 0;
        __syncthreads();
        if (t < 256) sc[t] += add;
        __syncthreads();
    }
    if (t < BDIV) {
        int e = sc[t] - v;  // exclusive prefix
        cur[t] = e;
        float dv = rsqrtf(1.0f + wsum[t]);  // +1 = self loop
        dvs[t] = dv;
        int n = b * BDIV + t;
        if (n < NN) {
            dinv[n] = dv;
            nodebase[n] = b * SORTCAP + e;
            const float4* xr = (const float4*)(x + (long)n * TT);
            float4 v0 = xr[0], v1 = xr[1], v2 = xr[2];
            uint4* xo = (uint4*)(xpb + ((long)n << 3));
            uint4 w0, w1;
            w0.x = bfpack(v0.x * dv, v0.y * dv);
            w0.y = bfpack(v0.z * dv, v0.w * dv);
            w0.z = bfpack(v1.x * dv, v1.y * dv);
            w0.w = bfpack(v1.z * dv, v1.w * dv);
            w1.x = bfpack(v2.x * dv, v2.y * dv);
            w1.y = bfpack(v2.z * dv, v2.w * dv);
            w1.z = 0u; w1.w = 0u;
            xo[0] = w0; xo[1] = w1;
        }
    }
    if (t == 0) bend[b] = b * SORTCAP + m;
    __syncthreads();
    // ---- sorted rewrite ----
    for (int k = t; k < m; k += 512) {
        int2 r = buf[k];
        int loc = (r.x >> 17) & 255;
        int p = atomicAdd(&cur[loc], 1);
        float w2 = __int_as_float(r.y) * dvs[loc];  // fold dinv[dst] into weight
        rec2[b * SORTCAP + p] = make_int2(r.x & 0x1FFFF, __float_as_int(w2));
    }
}

#define BLO(w) __uint_as_float((w) << 16)
#define BHI(w) __uint_as_float((w) & 0xFFFF0000u)

// 16 lanes per node — the measured optimum (R11; 32 lanes regressed in R12).
// Each lane walks every-16th record (coalesced rec2), one 32B bf16 row per
// edge, 4-level shfl reduce, 2 channels/lane exp2-domain epilogue. Bucket
// boundary (fixed-slot gaps in rec2) via bend[] for the bucket's last node.
__global__ __launch_bounds__(512) void k_fused(const int* __restrict__ nodebase,
                                               const int* __restrict__ bend,
                                               const int2* __restrict__ rec2,
                                               const float* __restrict__ dinv,
                                               const u32* __restrict__ xpb,
                                               const float* __restrict__ P,
                                               const float* __restrict__ hw,
                                               const float* __restrict__ hb,
                                               float* __restrict__ out) {
    int g = blockIdx.x * 512 + threadIdx.x;
    int n = g >> 4, sub = g & 15;   // NN*16 = 1.6M = 3125*512 exactly
    float a[TT];
#pragma unroll
    for (int q = 0; q < TT; ++q) a[q] = 0.f;
    if (sub == 0) {
        float di = dinv[n];   // self term = dinv * (bf16 row)
        const uint4* xr = (const uint4*)(xpb + ((long)n << 3));
        uint4 h0 = xr[0];
        uint2 h1 = *(const uint2*)(xr + 1);
        a[0]  = di * BLO(h0.x); a[1]  = di * BHI(h0.x);
        a[2]  = di * BLO(h0.y); a[3]  = di * BHI(h0.y);
        a[4]  = di * BLO(h0.z); a[5]  = di * BHI(h0.z);
        a[6]  = di * BLO(h0.w); a[7]  = di * BHI(h0.w);
        a[8]  = di * BLO(h1.x); a[9]  = di * BHI(h1.x);
        a[10] = di * BLO(h1.y); a[11] = di * BHI(h1.y);
    }
    int b = (u32)n / BDIV;
    int loc = n - b * BDIV;
    int k0 = nodebase[n];
    int k1 = (loc == BDIV - 1 || n == NN - 1) ? bend[b] : nodebase[n + 1];
    for (int k = k0 + sub; k < k1; k += 16) {
        int2 r = rec2[k];
        float c = __int_as_float(r.y);  // = ew * dinv[dst]; dinv[src] in xpb
        const uint4* xs = (const uint4*)(xpb + ((long)r.x << 3));
        uint4 h0 = xs[0];                       // periods 0-7 (16B)
        uint2 h1 = *(const uint2*)(xs + 1);     // periods 8-11 (8B, same line)
        a[0]  = fmaf(c, BLO(h0.x), a[0]);  a[1]  = fmaf(c, BHI(h0.x), a[1]);
        a[2]  = fmaf(c, BLO(h0.y), a[2]);  a[3]  = fmaf(c, BHI(h0.y), a[3]);
        a[4]  = fmaf(c, BLO(h0.z), a[4]);  a[5]  = fmaf(c, BHI(h0.z), a[5]);
        a[6]  = fmaf(c, BLO(h0.w), a[6]);  a[7]  = fmaf(c, BHI(h0.w), a[7]);
        a[8]  = fmaf(c, BLO(h1.x), a[8]);  a[9]  = fmaf(c, BHI(h1.x), a[9]);
        a[10] = fmaf(c, BLO(h1.y), a[10]); a[11] = fmaf(c, BHI(h1.y), a[11]);
    }
    // tree-reduce the 12 accumulators across the 16 lanes of this node
#pragma unroll
    for (int q = 0; q < TT; ++q) {
        float v = a[q];
        v += __shfl_xor(v, 1);
        v += __shfl_xor(v, 2);
        v += __shfl_xor(v, 4);
        v += __shfl_xor(v, 8);
        a[q] = v;
    }
    // --- epilogue: gates + attention + head, 2 hidden channels per lane ---
    float p[TT];
#pragma unroll
    for (int q = 0; q < TT; ++q) p[q] = P[4*HH + q];
    float o = 0.f;
#pragma unroll
    for (int jj = 0; jj < 2; ++jj) {
        int j = (jj << 4) | sub;
        float Az = P[j], Bz = P[HH + j], Ah2 = P[2*HH + j], Bh2 = P[3*HH + j];
        float w = hw[j];
        float acc = 0.f;
#pragma unroll
        for (int q = 0; q < TT; ++q) {
            float xz = fmaf(a[q], Az, Bz);                   // log2-domain
            float xh = fminf(fmaf(a[q], Ah2, Bh2), 115.f);   // keep eh finite
            float ez = __builtin_amdgcn_exp2f(xz);  // e^orig_xz
            float eh = __builtin_amdgcn_exp2f(xh);  // e^(2*orig_xh)
            float den = (1.f + ez) * (eh + 1.f);
            float num = eh - 1.f;
            acc = fmaf(p[q] * num, __builtin_amdgcn_rcpf(den), acc);
        }
        o = fmaf(fmaxf(acc, 0.f), w, o);
    }
    o += __shfl_xor(o, 1);
    o += __shfl_xor(o, 2);
    o += __shfl_xor(o, 4);
    o += __shfl_xor(o, 8);
    if (sub == 0) out[n] = o + hb[0];
}

extern "C" void kernel_launch(void* const* d_in, const int* in_sizes, int n_in,
                              void* d_out, int out_size, void* d_ws, size_t ws_size,
                              hipStream_t stream) {
    const float* x    = (const float*)d_in[0];
    const int*   ei   = (const int*)d_in[1];
    const float* ew   = (const float*)d_in[2];
    const float* att  = (const float*)d_in[3];
    const float* czw  = (const float*)d_in[4];
    const float* czb  = (const float*)d_in[5];
    const float* lzw  = (const float*)d_in[6];
    const float* lzb  = (const float*)d_in[7];
    // conv_r / lin_r (d_in[8..11]) are mathematically dead: H=0 -> H*R=0, Z*H=0.
    const float* chw  = (const float*)d_in[12];
    const float* chb  = (const float*)d_in[13];
    const float* lhw  = (const float*)d_in[14];
    const float* lhb  = (const float*)d_in[15];
    const float* hw   = (const float*)d_in[16];
    const float* hb   = (const float*)d_in[17];
    float* out = (float*)d_out;

    int*  ws32     = (int*)d_ws;
    int*  offT     = ws32;                     // NCH*513 = 262656
    int*  nodebase = ws32 + 262656;            // 100000
    int*  bend     = ws32 + 362656;            // 512
    float* dinv    = (float*)(ws32 + 363168);  // NN
    u32*  xpb      = (u32*)(ws32 + 463168);    // NN*8 u32, 32B rows (3.2MB)
    int2* rec      = (int2*)(ws32 + 1263168);  // NE int2 (chunk-ordered)
    int2* rec2     = (int2*)(ws32 + 4463168);  // NBUK*3776 int2 (node-sorted)
    float* P       = (float*)(ws32 + 8329792); // 144

    k_scatter<<<NCH + 1, 512, 0, stream>>>(ei, ew, rec, offT,
                                           czw, czb, lzw, lzb, chw, chb, lhw, lhb, att, P);
    k_sort<<<NBUK, 512, 0, stream>>>(rec, offT, rec2, nodebase, bend, dinv, x, xpb);
    k_fused<<<(NN * 16) / 512, 512, 0, stream>>>(nodebase, bend, rec2, dinv, xpb,
                                                 P, hw, hb, out);
}